// Round 3
// baseline (842.777 us; speedup 1.0000x reference)
//
#include <hip/hip_runtime.h>
#include <hip/hip_bf16.h>

#define BM 128
#define BN 128
#define BK 64   // 64 bf16 = 128B per LDS row; one barrier per K-step (2-phase dbuf)

typedef short short8 __attribute__((ext_vector_type(8)));
typedef float f32x4 __attribute__((ext_vector_type(4)));

using bf = __hip_bfloat16;

static const int NOSPLIT = 1 << 30;

// ---------------------------------------------------------------------------
// async 16B global -> LDS (direct DMA, no VGPR round-trip).
// HW semantics: per-lane dest = wave-uniform lds base + lane*16B.
// ---------------------------------------------------------------------------
__device__ __forceinline__ void gld16(const void* g, void* l)
{
    __builtin_amdgcn_global_load_lds(
        (__attribute__((address_space(1))) void*)g,
        (__attribute__((address_space(3))) void*)l, 16, 0, 0);
}

// LDS offset (ushorts) of k-group kg8 (8 bf16 = 16B slot, 8 slots/row) of row
// `row` under the XOR swizzle: slot = kg8 ^ (row&7). Measured
// SQ_LDS_BANK_CONFLICT = 0 with this layout.
__device__ __forceinline__ int lofs(int row, int kg8)
{
    return row * 64 + ((kg8 ^ (row & 7)) << 3);
}

// ---------------------------------------------------------------------------
// fp32 -> bf16 cast, 4 elems/thread
// ---------------------------------------------------------------------------
__global__ __launch_bounds__(256)
void cast_bf16(const float* __restrict__ src, bf* __restrict__ dst, int n)
{
    int i = (blockIdx.x * 256 + threadIdx.x) * 4;
    if (i >= n) return;
    float4 v = *(const float4*)(src + i);
    bf o[4] = { __float2bfloat16(v.x), __float2bfloat16(v.y),
                __float2bfloat16(v.z), __float2bfloat16(v.w) };
    *(uint2*)(dst + i) = *(const uint2*)o;
}

// ---------------------------------------------------------------------------
// W [Kd][Nd] fp32 -> Wt [Nd][Kd] bf16 via 32x32 LDS tile (+1 pad)
// ---------------------------------------------------------------------------
__global__ __launch_bounds__(256)
void transpose_cast_w(const float* __restrict__ W, bf* __restrict__ Wt,
                      int Kd, int Nd)
{
    __shared__ float tile[32][33];
    int k0 = blockIdx.y * 32, n0 = blockIdx.x * 32;
    int t = threadIdx.x;
    int r = t >> 3, c = (t & 7) * 4;
    float4 v = *(const float4*)(W + (size_t)(k0 + r) * Nd + n0 + c);
    tile[r][c] = v.x; tile[r][c+1] = v.y; tile[r][c+2] = v.z; tile[r][c+3] = v.w;
    __syncthreads();
    bf o[4] = { __float2bfloat16(tile[c][r]),   __float2bfloat16(tile[c+1][r]),
                __float2bfloat16(tile[c+2][r]), __float2bfloat16(tile[c+3][r]) };
    *(uint2*)(Wt + (size_t)(n0 + r) * Kd + k0 + c) = *(const uint2*)o;
}

// ---------------------------------------------------------------------------
// C = A[M,K] @ Bt[N,K]^T + bias; bf16 in, fp32 acc. 2-phase double-buffered:
// issue async global_load_lds for tile t+1, compute tile t, single barrier.
// The barrier's implicit vmcnt(0) then waits for loads that had the whole
// compute phase to progress (latency hiding without manual waitcnt).
// TC: write C transposed (Ct[n][m], 8B packed). Split-A at k=splitA.
// ---------------------------------------------------------------------------
template <typename CT, bool TC>
__global__ __launch_bounds__(256)
void gemm_nt(const bf* __restrict__ A, const bf* __restrict__ A2, int splitA, int lda,
             const bf* __restrict__ Bt, int ldb,
             const float* __restrict__ bias, CT* __restrict__ C, int ldc,
             int K, long long strA, long long strB, long long strC)
{
    __shared__ __align__(16) ushort sA[2][BM * 64];   // 2 x 16 KB
    __shared__ __align__(16) ushort sB[2][BN * 64];

    const int z = blockIdx.z;
    A  += (long long)z * strA;
    A2 += (long long)z * strA;
    Bt += (long long)z * strB;
    C  += (long long)z * strC;

    const int t = threadIdx.x;
    const int m0 = blockIdx.x * BM;
    const int n0 = blockIdx.y * BN;
    const int wave = t >> 6, lane = t & 63;
    const int wm = wave >> 1, wn = wave & 1;
    const int lcol = lane & 15, quad = lane >> 4;
    const int rl = lane >> 3, cslot = lane & 7;    // staging: 8 rows x 8 16B-slots

    auto stage = [&](int kt, int c) {
        const bf* Asrc = (kt < splitA) ? A : A2;
        const int ktt = (kt < splitA) ? kt : kt - splitA;
        #pragma unroll
        for (int it = 0; it < 4; ++it) {
            int br  = it * 32 + wave * 8;           // wave-uniform base row
            int row = br + rl;
            int kg  = cslot ^ rl;                   // source-side swizzle
            gld16(Asrc + (size_t)(m0 + row) * lda + ktt + kg * 8, &sA[c][br * 64]);
            gld16(Bt   + (size_t)(n0 + row) * ldb + kt  + kg * 8, &sB[c][br * 64]);
        }
    };

    f32x4 acc[4][4] = {};

    stage(0, 0);
    __syncthreads();
    int cur = 0;
    for (int kt = 0; kt < K; kt += BK) {
        if (kt + BK < K) stage(kt + BK, cur ^ 1);   // prefetch next tile

        #pragma unroll
        for (int h = 0; h < 2; ++h) {
            short8 af[4], bfr[4];
            #pragma unroll
            for (int i = 0; i < 4; ++i)
                af[i] = *(const short8*)&sA[cur][lofs(wm * 64 + i * 16 + lcol, h * 4 + quad)];
            #pragma unroll
            for (int j = 0; j < 4; ++j)
                bfr[j] = *(const short8*)&sB[cur][lofs(wn * 64 + j * 16 + lcol, h * 4 + quad)];
            #pragma unroll
            for (int i = 0; i < 4; ++i)
                #pragma unroll
                for (int j = 0; j < 4; ++j)
                    acc[i][j] = __builtin_amdgcn_mfma_f32_16x16x32_bf16(af[i], bfr[j], acc[i][j], 0, 0, 0);
        }
        __syncthreads();   // drains my DMA issues + joins waves (1 barrier/step)
        cur ^= 1;
    }

    #pragma unroll
    for (int j = 0; j < 4; ++j) {
        int col = n0 + wn * 64 + j * 16 + lcol;
        float bv = bias ? bias[col] : 0.0f;
        #pragma unroll
        for (int i = 0; i < 4; ++i) {
            int row = m0 + wm * 64 + i * 16 + quad * 4;
            if (!TC) {
                #pragma unroll
                for (int r4 = 0; r4 < 4; ++r4)
                    C[(size_t)(row + r4) * ldc + col] = (CT)(acc[i][j][r4] + bv);
            } else {
                bf o[4];
                #pragma unroll
                for (int r4 = 0; r4 < 4; ++r4)
                    o[r4] = __float2bfloat16(acc[i][j][r4] + bv);
                *(uint2*)((bf*)C + (size_t)col * ldc + row) = *(const uint2*)o;
            }
        }
    }
}

// ---------------------------------------------------------------------------
// E[q,k] = exp((Q[q,:].K[k,:]) * rscale) + colsum over q (softmax over QUERY
// axis). z-batched. Grid (S/BM, S/BN, cb). S = 2048 fixed.
// MFMA operands SWAPPED (K-frag first) so the C/D register group holds 4
// consecutive k: E row-stores are packed 8B. Colsum reduces across the
// 16-lane lcol group. Same 2-phase dbuf structure as gemm_nt.
// ---------------------------------------------------------------------------
__global__ __launch_bounds__(256)
void scores_exp(const bf* __restrict__ Q, const bf* __restrict__ Km,
                bf* __restrict__ E, float* __restrict__ colsum,
                int Dd, float rscale)
{
    const int S = 2048;
    __shared__ __align__(16) ushort sA[2][BM * 64];
    __shared__ __align__(16) ushort sB[2][BN * 64];

    const int z = blockIdx.z;
    Q  += (size_t)z * S * Dd;
    Km += (size_t)z * S * Dd;
    E  += (size_t)z * S * S;
    colsum += (size_t)z * S;

    const int t = threadIdx.x;
    const int m0 = blockIdx.x * BM;     // Q rows
    const int n0 = blockIdx.y * BN;     // K rows
    const int wave = t >> 6, lane = t & 63;
    const int wm = wave >> 1, wn = wave & 1;
    const int lcol = lane & 15, quad = lane >> 4;
    const int rl = lane >> 3, cslot = lane & 7;

    auto stage = [&](int kt, int c) {
        #pragma unroll
        for (int it = 0; it < 4; ++it) {
            int br  = it * 32 + wave * 8;
            int row = br + rl;
            int kg  = cslot ^ rl;
            gld16(Q  + (size_t)(m0 + row) * Dd + kt + kg * 8, &sA[c][br * 64]);
            gld16(Km + (size_t)(n0 + row) * Dd + kt + kg * 8, &sB[c][br * 64]);
        }
    };

    f32x4 acc[4][4] = {};       // acc[a][b]: rows = K-range a, cols = Q-range b

    stage(0, 0);
    __syncthreads();
    int cur = 0;
    for (int kt = 0; kt < Dd; kt += BK) {
        if (kt + BK < Dd) stage(kt + BK, cur ^ 1);

        #pragma unroll
        for (int h = 0; h < 2; ++h) {
            short8 af[4], bfr[4];
            #pragma unroll
            for (int i = 0; i < 4; ++i)
                af[i] = *(const short8*)&sA[cur][lofs(wm * 64 + i * 16 + lcol, h * 4 + quad)];
            #pragma unroll
            for (int j = 0; j < 4; ++j)
                bfr[j] = *(const short8*)&sB[cur][lofs(wn * 64 + j * 16 + lcol, h * 4 + quad)];
            #pragma unroll
            for (int a = 0; a < 4; ++a)
                #pragma unroll
                for (int b = 0; b < 4; ++b)
                    acc[a][b] = __builtin_amdgcn_mfma_f32_16x16x32_bf16(bfr[a], af[b], acc[a][b], 0, 0, 0);
        }
        __syncthreads();
        cur ^= 1;
    }

    // epilogue: rows of the C tile are k (first operand = K fragments),
    // cols are q. Register r4 walks 4 consecutive k -> packed 8B stores.
    #pragma unroll
    for (int a = 0; a < 4; ++a) {
        const int kk = n0 + wn * 64 + a * 16 + quad * 4;
        f32x4 csum = {0.f, 0.f, 0.f, 0.f};
        #pragma unroll
        for (int b = 0; b < 4; ++b) {
            const int q = m0 + wm * 64 + b * 16 + lcol;
            bf o[4];
            #pragma unroll
            for (int r = 0; r < 4; ++r) {
                float e = __expf(acc[a][b][r] * rscale);
                o[r] = __float2bfloat16(e);
                csum[r] += e;
            }
            *(uint2*)(E + (size_t)q * S + kk) = *(const uint2*)o;
        }
        // reduce over q within the wave: 16-lane lcol group (quad preserved)
        #pragma unroll
        for (int msk = 1; msk < 16; msk <<= 1) {
            csum[0] += __shfl_xor(csum[0], msk);
            csum[1] += __shfl_xor(csum[1], msk);
            csum[2] += __shfl_xor(csum[2], msk);
            csum[3] += __shfl_xor(csum[3], msk);
        }
        if (lcol == 0) {
            atomicAdd(&colsum[kk + 0], csum[0]);
            atomicAdd(&colsum[kk + 1], csum[1]);
            atomicAdd(&colsum[kk + 2], csum[2]);
            atomicAdd(&colsum[kk + 3], csum[3]);
        }
    }
}

// Vt[d][col] /= cs[col], over a column window. Grid (ncols/1024, 768).
__global__ __launch_bounds__(256)
void scale_vt(bf* __restrict__ Vt, const float* __restrict__ cs, int ldv)
{
    int col = (blockIdx.x * 256 + threadIdx.x) * 4;
    bf* p = Vt + (size_t)blockIdx.y * ldv + col;
    bf v[4]; *(uint2*)v = *(const uint2*)p;
    float4 c4 = *(const float4*)(cs + col);
    v[0] = __float2bfloat16(__bfloat162float(v[0]) / c4.x);
    v[1] = __float2bfloat16(__bfloat162float(v[1]) / c4.y);
    v[2] = __float2bfloat16(__bfloat162float(v[2]) / c4.z);
    v[3] = __float2bfloat16(__bfloat162float(v[3]) / c4.w);
    *(uint2*)p = *(const uint2*)v;
}

// gating from fp32 originals: F1 = a2*sx+(1-a2)*cx ; F2 = a1*cx+(1-a1)*sx
__global__ __launch_bounds__(256)
void gate_fuse(const bf* __restrict__ O1, const bf* __restrict__ O2,
               const float* __restrict__ SX, const float* __restrict__ CX,
               bf* __restrict__ F1, bf* __restrict__ F2, int n)
{
    int i = (blockIdx.x * 256 + threadIdx.x) * 4;
    if (i >= n) return;
    bf o1[4], o2[4], f1[4], f2[4];
    *(uint2*)o1 = *(const uint2*)(O1 + i);
    *(uint2*)o2 = *(const uint2*)(O2 + i);
    float4 sx = *(const float4*)(SX + i);
    float4 cx = *(const float4*)(CX + i);
    #pragma unroll
    for (int e = 0; e < 4; ++e) {
        float s = (&sx.x)[e], c = (&cx.x)[e];
        float a1 = 1.0f / (1.0f + __expf(-tanhf(__bfloat162float(o1[e]))));
        float a2 = 1.0f / (1.0f + __expf(-tanhf(__bfloat162float(o2[e]))));
        f1[e] = __float2bfloat16(a2 * s + (1.0f - a2) * c);
        f2[e] = __float2bfloat16(a1 * c + (1.0f - a1) * s);
    }
    *(uint2*)(F1 + i) = *(const uint2*)f1;
    *(uint2*)(F2 + i) = *(const uint2*)f2;
}

extern "C" void kernel_launch(void* const* d_in, const int* in_sizes, int n_in,
                              void* d_out, int out_size, void* d_ws, size_t ws_size,
                              hipStream_t stream)
{
    const int B = 8, S = 2048, D = 768;
    const int M = B * S;                        // 16384

    const float* SX = (const float*)d_in[0];
    const float* CX = (const float*)d_in[1];
    const float* Wsrc[7] = { (const float*)d_in[2],  (const float*)d_in[4],
                             (const float*)d_in[6],  (const float*)d_in[8],
                             (const float*)d_in[10], (const float*)d_in[12],
                             (const float*)d_in[14] };
    const float* bias[7] = { (const float*)d_in[3],  (const float*)d_in[5],
                             (const float*)d_in[7],  (const float*)d_in[9],
                             (const float*)d_in[11], (const float*)d_in[13],
                             (const float*)d_in[15] };
    float* out = (float*)d_out;

    // ---- workspace layout: fixed 160.6 MB + adaptive E chunk ----
    char* w = (char*)d_ws;
    const size_t MD  = (size_t)M * D * sizeof(bf);       // 25.17 MB
    const size_t WSZ = (size_t)D * D * sizeof(bf);       // 1.18 MB
    const size_t SSB = (size_t)S * S * sizeof(bf);       // 8.39 MB per E batch
    bf* Xs = (bf*)(w);
    bf* Xc = (bf*)(w + MD);
    bf* Wt[7];
    for (int i = 0; i < 7; ++i) Wt[i] = (bf*)(w + 2 * MD + i * WSZ);  // Wtf = slots 6,7
    char* base2 = w + 2 * MD + 8 * WSZ;
    bf* Q  = (bf*)(base2);
    bf* Kb = (bf*)(base2 + MD);
    bf* Vt = (bf*)(base2 + 2 * MD);
    bf* O1 = (bf*)(base2 + 3 * MD);
    float* cs = (float*)(base2 + 4 * MD);                // 2*B*S fp32 = 128 KB
    char* Eb0 = base2 + 4 * MD + (size_t)2 * B * S * sizeof(float);
    bf* E = (bf*)Eb0;
    int cb;
    {
        size_t fixed = (size_t)(Eb0 - w);
        size_t avail = ws_size > fixed ? ws_size - fixed : SSB;
        long long c = (long long)(avail / SSB);
        cb = c < 1 ? 1 : (c > 8 ? 8 : (int)c);
    }
    // aliases (stream-order verified in r6, which passed):
    bf* O2 = Xs;
    bf* F1 = Kb;
    bf* F2 = Vt;

    (void)hipMemsetAsync(cs, 0, (size_t)2 * B * S * sizeof(float), stream);

    dim3 blk(256);
    {
        int n = M * D;
        cast_bf16<<<dim3(n / 1024), blk, 0, stream>>>(SX, Xs, n);
        cast_bf16<<<dim3(n / 1024), blk, 0, stream>>>(CX, Xc, n);
        for (int i = 0; i < 6; ++i)
            transpose_cast_w<<<dim3(D / 32, D / 32), blk, 0, stream>>>(Wsrc[i], Wt[i], D, D);
        transpose_cast_w<<<dim3(D / 32, 2 * D / 32), blk, 0, stream>>>(Wsrc[6], Wt[6], 2 * D, D);
    }

    dim3 gProj(M / BM, D / BN);      // 128 x 6
    const float rscale = 1.0f / sqrtf((float)D);
    const size_t SD = (size_t)S * D;
    const long long SS = (long long)S * S;

    for (int dir = 0; dir < 2; ++dir) {
        const bf* Xq = dir == 0 ? Xs : Xc;   // queries source
        const bf* Xk = dir == 0 ? Xc : Xs;   // keys/values source
        bf* Wq = Wt[dir * 3 + 0];
        bf* Wk = Wt[dir * 3 + 1];
        bf* Wv = Wt[dir * 3 + 2];
        const float* bq = bias[dir * 3 + 0];
        const float* bk = bias[dir * 3 + 1];
        const float* bv = bias[dir * 3 + 2];
        bf* O = dir == 0 ? O1 : O2;
        float* csd = cs + (size_t)dir * B * S;

        gemm_nt<bf, false><<<gProj, blk, 0, stream>>>(Xq, Xq, NOSPLIT, D, Wq, D, bq, Q,  D, D, 0, 0, 0);
        gemm_nt<bf, false><<<gProj, blk, 0, stream>>>(Xk, Xk, NOSPLIT, D, Wk, D, bk, Kb, D, D, 0, 0, 0);
        gemm_nt<bf, true ><<<gProj, blk, 0, stream>>>(Xk, Xk, NOSPLIT, D, Wv, D, bv, Vt, M, D, 0, 0, 0);

        for (int c0 = 0; c0 < B; c0 += cb) {
            int cbc = (B - c0 < cb) ? (B - c0) : cb;
            scores_exp<<<dim3(S / BM, S / BN, cbc), blk, 0, stream>>>(
                Q + c0 * SD, Kb + c0 * SD, E, csd + (size_t)c0 * S, D, rscale);
            scale_vt<<<dim3(cbc * S / 1024, D), blk, 0, stream>>>(
                Vt + (size_t)c0 * S, csd + (size_t)c0 * S, M);
            gemm_nt<bf, false><<<dim3(S / BM, D / BN, cbc), blk, 0, stream>>>(
                E, E, NOSPLIT, S, Vt + (size_t)c0 * S, M, nullptr,
                O + c0 * SD, D, S, SS, S, (long long)SD);
        }
    }

    // ---- gate (fp32 originals) + final split-A GEMM -> fp32 out ----
    gate_fuse<<<dim3(M * D / 1024), blk, 0, stream>>>(O1, O2, SX, CX, F1, F2, M * D);
    gemm_nt<float, false><<<gProj, blk, 0, stream>>>(F1, F2, D, D, Wt[6], 2 * D,
                                                     bias[6], out, D, 2 * D, 0, 0, 0);
}

// Round 4
// 740.564 us; speedup vs baseline: 1.1380x; 1.1380x over previous
//
#include <hip/hip_runtime.h>
#include <hip/hip_bf16.h>

#define BM 256   // 256x128 tile, 8 waves (512 thr): 2x MFMA per barrier vs 128x128
#define BN 128
#define BK 64    // 64 bf16 = 128B per LDS row; single-buffered (dbuf regressed: r3)

typedef short short8 __attribute__((ext_vector_type(8)));
typedef float f32x4 __attribute__((ext_vector_type(4)));

using bf = __hip_bfloat16;

static const int NOSPLIT = 1 << 30;

// ---------------------------------------------------------------------------
// async 16B global -> LDS (direct DMA, no VGPR round-trip).
// HW semantics: per-lane dest = wave-uniform lds base + lane*16B.
// ---------------------------------------------------------------------------
__device__ __forceinline__ void gld16(const void* g, void* l)
{
    __builtin_amdgcn_global_load_lds(
        (__attribute__((address_space(1))) void*)g,
        (__attribute__((address_space(3))) void*)l, 16, 0, 0);
}

// LDS offset (ushorts) of k-group kg8 (8 bf16 = 16B slot, 8 slots/row) of row
// `row` under the XOR swizzle: slot = kg8 ^ (row&7). Staging base rows are
// multiples of 8 so writer/reader permutations match. Measured
// SQ_LDS_BANK_CONFLICT = 0 with this layout.
__device__ __forceinline__ int lofs(int row, int kg8)
{
    return row * 64 + ((kg8 ^ (row & 7)) << 3);
}

// ---------------------------------------------------------------------------
// fp32 -> bf16 cast, 4 elems/thread
// ---------------------------------------------------------------------------
__global__ __launch_bounds__(256)
void cast_bf16(const float* __restrict__ src, bf* __restrict__ dst, int n)
{
    int i = (blockIdx.x * 256 + threadIdx.x) * 4;
    if (i >= n) return;
    float4 v = *(const float4*)(src + i);
    bf o[4] = { __float2bfloat16(v.x), __float2bfloat16(v.y),
                __float2bfloat16(v.z), __float2bfloat16(v.w) };
    *(uint2*)(dst + i) = *(const uint2*)o;
}

// ---------------------------------------------------------------------------
// W [Kd][Nd] fp32 -> Wt [Nd][Kd] bf16 via 32x32 LDS tile (+1 pad)
// ---------------------------------------------------------------------------
__global__ __launch_bounds__(256)
void transpose_cast_w(const float* __restrict__ W, bf* __restrict__ Wt,
                      int Kd, int Nd)
{
    __shared__ float tile[32][33];
    int k0 = blockIdx.y * 32, n0 = blockIdx.x * 32;
    int t = threadIdx.x;
    int r = t >> 3, c = (t & 7) * 4;
    float4 v = *(const float4*)(W + (size_t)(k0 + r) * Nd + n0 + c);
    tile[r][c] = v.x; tile[r][c+1] = v.y; tile[r][c+2] = v.z; tile[r][c+3] = v.w;
    __syncthreads();
    bf o[4] = { __float2bfloat16(tile[c][r]),   __float2bfloat16(tile[c+1][r]),
                __float2bfloat16(tile[c+2][r]), __float2bfloat16(tile[c+3][r]) };
    *(uint2*)(Wt + (size_t)(n0 + r) * Kd + k0 + c) = *(const uint2*)o;
}

// ---------------------------------------------------------------------------
// C = A[M,K] @ Bt[N,K]^T + bias; bf16 in, fp32 acc. 256x128 tile, 8 waves
// (4 wm x 2 wn, each wave owns 64x64). Staging via async global_load_lds
// into the swizzled unpadded BK=64 tile (48 KB total, single-buffered);
// two k=32 halves run sequentially inside one barrier pair.
// TC: write C transposed (Ct[n][m], 8B packed). Split-A at k=splitA.
// ---------------------------------------------------------------------------
template <typename CT, bool TC>
__global__ __launch_bounds__(512)
void gemm_nt(const bf* __restrict__ A, const bf* __restrict__ A2, int splitA, int lda,
             const bf* __restrict__ Bt, int ldb,
             const float* __restrict__ bias, CT* __restrict__ C, int ldc,
             int K, long long strA, long long strB, long long strC)
{
    __shared__ __align__(16) ushort sA[BM * 64];   // 32 KB
    __shared__ __align__(16) ushort sB[BN * 64];   // 16 KB

    const int z = blockIdx.z;
    A  += (long long)z * strA;
    A2 += (long long)z * strA;
    Bt += (long long)z * strB;
    C  += (long long)z * strC;

    const int t = threadIdx.x;
    const int m0 = blockIdx.x * BM;
    const int n0 = blockIdx.y * BN;
    const int wave = t >> 6, lane = t & 63;        // 8 waves
    const int wm = wave >> 1, wn = wave & 1;       // 4 x 2
    const int lcol = lane & 15, quad = lane >> 4;
    const int rl = lane >> 3, cslot = lane & 7;    // staging: 8 rows x 8 16B-slots

    f32x4 acc[4][4] = {};

    for (int kt = 0; kt < K; kt += BK) {
        const bf* Asrc = (kt < splitA) ? A : A2;
        const int ktt = (kt < splitA) ? kt : kt - splitA;
        const int kg = cslot ^ rl;                  // source-side swizzle
        #pragma unroll
        for (int it = 0; it < 4; ++it) {            // A: 256 rows, 8 waves x 8 rows x 4
            int br  = it * 64 + wave * 8;           // wave-uniform base row
            int row = br + rl;
            gld16(Asrc + (size_t)(m0 + row) * lda + ktt + kg * 8, &sA[br * 64]);
        }
        #pragma unroll
        for (int it = 0; it < 2; ++it) {            // B: 128 rows, 8 waves x 8 rows x 2
            int br  = it * 64 + wave * 8;
            int row = br + rl;
            gld16(Bt + (size_t)(n0 + row) * ldb + kt + kg * 8, &sB[br * 64]);
        }
        __syncthreads();   // drains vmcnt (async DMA) + joins waves

        #pragma unroll
        for (int h = 0; h < 2; ++h) {
            short8 af[4], bfr[4];
            #pragma unroll
            for (int i = 0; i < 4; ++i)
                af[i] = *(const short8*)&sA[lofs(wm * 64 + i * 16 + lcol, h * 4 + quad)];
            #pragma unroll
            for (int j = 0; j < 4; ++j)
                bfr[j] = *(const short8*)&sB[lofs(wn * 64 + j * 16 + lcol, h * 4 + quad)];
            #pragma unroll
            for (int i = 0; i < 4; ++i)
                #pragma unroll
                for (int j = 0; j < 4; ++j)
                    acc[i][j] = __builtin_amdgcn_mfma_f32_16x16x32_bf16(af[i], bfr[j], acc[i][j], 0, 0, 0);
        }
        __syncthreads();
    }

    #pragma unroll
    for (int j = 0; j < 4; ++j) {
        int col = n0 + wn * 64 + j * 16 + lcol;
        float bv = bias ? bias[col] : 0.0f;
        #pragma unroll
        for (int i = 0; i < 4; ++i) {
            int row = m0 + wm * 64 + i * 16 + quad * 4;
            if (!TC) {
                #pragma unroll
                for (int r4 = 0; r4 < 4; ++r4)
                    C[(size_t)(row + r4) * ldc + col] = (CT)(acc[i][j][r4] + bv);
            } else {
                bf o[4];
                #pragma unroll
                for (int r4 = 0; r4 < 4; ++r4)
                    o[r4] = __float2bfloat16(acc[i][j][r4] + bv);
                *(uint2*)((bf*)C + (size_t)col * ldc + row) = *(const uint2*)o;
            }
        }
    }
}

// ---------------------------------------------------------------------------
// E[q,k] = exp((Q[q,:].K[k,:]) * rscale) + colsum over q (softmax over QUERY
// axis). z-batched. Grid (S/BM, S/BN, cb). S = 2048 fixed.
// 256(q) x 128(k) tile, 8 waves. MFMA operands SWAPPED (K-frag first) so the
// C/D register group holds 4 consecutive k: E row-stores are packed 8B.
// Colsum (reduce over q) reduces across the 16-lane lcol group.
// ---------------------------------------------------------------------------
__global__ __launch_bounds__(512)
void scores_exp(const bf* __restrict__ Q, const bf* __restrict__ Km,
                bf* __restrict__ E, float* __restrict__ colsum,
                int Dd, float rscale)
{
    const int S = 2048;
    __shared__ __align__(16) ushort sA[BM * 64];
    __shared__ __align__(16) ushort sB[BN * 64];

    const int z = blockIdx.z;
    Q  += (size_t)z * S * Dd;
    Km += (size_t)z * S * Dd;
    E  += (size_t)z * S * S;
    colsum += (size_t)z * S;

    const int t = threadIdx.x;
    const int m0 = blockIdx.x * BM;     // Q rows
    const int n0 = blockIdx.y * BN;     // K rows
    const int wave = t >> 6, lane = t & 63;
    const int wm = wave >> 1, wn = wave & 1;
    const int lcol = lane & 15, quad = lane >> 4;
    const int rl = lane >> 3, cslot = lane & 7;

    f32x4 acc[4][4] = {};       // acc[a][b]: rows = K-range a, cols = Q-range b

    for (int kt = 0; kt < Dd; kt += BK) {
        const int kg = cslot ^ rl;
        #pragma unroll
        for (int it = 0; it < 4; ++it) {
            int br  = it * 64 + wave * 8;
            int row = br + rl;
            gld16(Q + (size_t)(m0 + row) * Dd + kt + kg * 8, &sA[br * 64]);
        }
        #pragma unroll
        for (int it = 0; it < 2; ++it) {
            int br  = it * 64 + wave * 8;
            int row = br + rl;
            gld16(Km + (size_t)(n0 + row) * Dd + kt + kg * 8, &sB[br * 64]);
        }
        __syncthreads();

        #pragma unroll
        for (int h = 0; h < 2; ++h) {
            short8 af[4], bfr[4];
            #pragma unroll
            for (int i = 0; i < 4; ++i)
                af[i] = *(const short8*)&sA[lofs(wm * 64 + i * 16 + lcol, h * 4 + quad)];
            #pragma unroll
            for (int j = 0; j < 4; ++j)
                bfr[j] = *(const short8*)&sB[lofs(wn * 64 + j * 16 + lcol, h * 4 + quad)];
            #pragma unroll
            for (int a = 0; a < 4; ++a)
                #pragma unroll
                for (int b = 0; b < 4; ++b)
                    acc[a][b] = __builtin_amdgcn_mfma_f32_16x16x32_bf16(bfr[a], af[b], acc[a][b], 0, 0, 0);
        }
        __syncthreads();
    }

    // epilogue: rows of the C tile are k (first operand = K fragments),
    // cols are q. Register r4 walks 4 consecutive k -> packed 8B stores.
    #pragma unroll
    for (int a = 0; a < 4; ++a) {
        const int kk = n0 + wn * 64 + a * 16 + quad * 4;
        f32x4 csum = {0.f, 0.f, 0.f, 0.f};
        #pragma unroll
        for (int b = 0; b < 4; ++b) {
            const int q = m0 + wm * 64 + b * 16 + lcol;
            bf o[4];
            #pragma unroll
            for (int r = 0; r < 4; ++r) {
                float e = __expf(acc[a][b][r] * rscale);
                o[r] = __float2bfloat16(e);
                csum[r] += e;
            }
            *(uint2*)(E + (size_t)q * S + kk) = *(const uint2*)o;
        }
        // reduce over q within the wave: 16-lane lcol group (quad preserved)
        #pragma unroll
        for (int msk = 1; msk < 16; msk <<= 1) {
            csum[0] += __shfl_xor(csum[0], msk);
            csum[1] += __shfl_xor(csum[1], msk);
            csum[2] += __shfl_xor(csum[2], msk);
            csum[3] += __shfl_xor(csum[3], msk);
        }
        if (lcol == 0) {
            atomicAdd(&colsum[kk + 0], csum[0]);
            atomicAdd(&colsum[kk + 1], csum[1]);
            atomicAdd(&colsum[kk + 2], csum[2]);
            atomicAdd(&colsum[kk + 3], csum[3]);
        }
    }
}

// Vt[d][col] /= cs[col], over a column window. Grid (ncols/1024, 768).
__global__ __launch_bounds__(256)
void scale_vt(bf* __restrict__ Vt, const float* __restrict__ cs, int ldv)
{
    int col = (blockIdx.x * 256 + threadIdx.x) * 4;
    bf* p = Vt + (size_t)blockIdx.y * ldv + col;
    bf v[4]; *(uint2*)v = *(const uint2*)p;
    float4 c4 = *(const float4*)(cs + col);
    v[0] = __float2bfloat16(__bfloat162float(v[0]) / c4.x);
    v[1] = __float2bfloat16(__bfloat162float(v[1]) / c4.y);
    v[2] = __float2bfloat16(__bfloat162float(v[2]) / c4.z);
    v[3] = __float2bfloat16(__bfloat162float(v[3]) / c4.w);
    *(uint2*)p = *(const uint2*)v;
}

// gating from fp32 originals: F1 = a2*sx+(1-a2)*cx ; F2 = a1*cx+(1-a1)*sx
__global__ __launch_bounds__(256)
void gate_fuse(const bf* __restrict__ O1, const bf* __restrict__ O2,
               const float* __restrict__ SX, const float* __restrict__ CX,
               bf* __restrict__ F1, bf* __restrict__ F2, int n)
{
    int i = (blockIdx.x * 256 + threadIdx.x) * 4;
    if (i >= n) return;
    bf o1[4], o2[4], f1[4], f2[4];
    *(uint2*)o1 = *(const uint2*)(O1 + i);
    *(uint2*)o2 = *(const uint2*)(O2 + i);
    float4 sx = *(const float4*)(SX + i);
    float4 cx = *(const float4*)(CX + i);
    #pragma unroll
    for (int e = 0; e < 4; ++e) {
        float s = (&sx.x)[e], c = (&cx.x)[e];
        float a1 = 1.0f / (1.0f + __expf(-tanhf(__bfloat162float(o1[e]))));
        float a2 = 1.0f / (1.0f + __expf(-tanhf(__bfloat162float(o2[e]))));
        f1[e] = __float2bfloat16(a2 * s + (1.0f - a2) * c);
        f2[e] = __float2bfloat16(a1 * c + (1.0f - a1) * s);
    }
    *(uint2*)(F1 + i) = *(const uint2*)f1;
    *(uint2*)(F2 + i) = *(const uint2*)f2;
}

extern "C" void kernel_launch(void* const* d_in, const int* in_sizes, int n_in,
                              void* d_out, int out_size, void* d_ws, size_t ws_size,
                              hipStream_t stream)
{
    const int B = 8, S = 2048, D = 768;
    const int M = B * S;                        // 16384

    const float* SX = (const float*)d_in[0];
    const float* CX = (const float*)d_in[1];
    const float* Wsrc[7] = { (const float*)d_in[2],  (const float*)d_in[4],
                             (const float*)d_in[6],  (const float*)d_in[8],
                             (const float*)d_in[10], (const float*)d_in[12],
                             (const float*)d_in[14] };
    const float* bias[7] = { (const float*)d_in[3],  (const float*)d_in[5],
                             (const float*)d_in[7],  (const float*)d_in[9],
                             (const float*)d_in[11], (const float*)d_in[13],
                             (const float*)d_in[15] };
    float* out = (float*)d_out;

    // ---- workspace layout: fixed 160.6 MB + adaptive E chunk ----
    char* w = (char*)d_ws;
    const size_t MD  = (size_t)M * D * sizeof(bf);       // 25.17 MB
    const size_t WSZ = (size_t)D * D * sizeof(bf);       // 1.18 MB
    const size_t SSB = (size_t)S * S * sizeof(bf);       // 8.39 MB per E batch
    bf* Xs = (bf*)(w);
    bf* Xc = (bf*)(w + MD);
    bf* Wt[7];
    for (int i = 0; i < 7; ++i) Wt[i] = (bf*)(w + 2 * MD + i * WSZ);  // Wtf = slots 6,7
    char* base2 = w + 2 * MD + 8 * WSZ;
    bf* Q  = (bf*)(base2);
    bf* Kb = (bf*)(base2 + MD);
    bf* Vt = (bf*)(base2 + 2 * MD);
    bf* O1 = (bf*)(base2 + 3 * MD);
    float* cs = (float*)(base2 + 4 * MD);                // 2*B*S fp32 = 128 KB
    char* Eb0 = base2 + 4 * MD + (size_t)2 * B * S * sizeof(float);
    bf* E = (bf*)Eb0;
    int cb;
    {
        size_t fixed = (size_t)(Eb0 - w);
        size_t avail = ws_size > fixed ? ws_size - fixed : SSB;
        long long c = (long long)(avail / SSB);
        cb = c < 1 ? 1 : (c > 8 ? 8 : (int)c);
    }
    // aliases (stream-order verified in r6, which passed):
    bf* O2 = Xs;
    bf* F1 = Kb;
    bf* F2 = Vt;

    (void)hipMemsetAsync(cs, 0, (size_t)2 * B * S * sizeof(float), stream);

    dim3 blk(256);
    dim3 blkG(512);
    {
        int n = M * D;
        cast_bf16<<<dim3(n / 1024), blk, 0, stream>>>(SX, Xs, n);
        cast_bf16<<<dim3(n / 1024), blk, 0, stream>>>(CX, Xc, n);
        for (int i = 0; i < 6; ++i)
            transpose_cast_w<<<dim3(D / 32, D / 32), blk, 0, stream>>>(Wsrc[i], Wt[i], D, D);
        transpose_cast_w<<<dim3(D / 32, 2 * D / 32), blk, 0, stream>>>(Wsrc[6], Wt[6], 2 * D, D);
    }

    dim3 gProj(M / BM, D / BN);      // 64 x 6
    const float rscale = 1.0f / sqrtf((float)D);
    const size_t SD = (size_t)S * D;
    const long long SS = (long long)S * S;

    for (int dir = 0; dir < 2; ++dir) {
        const bf* Xq = dir == 0 ? Xs : Xc;   // queries source
        const bf* Xk = dir == 0 ? Xc : Xs;   // keys/values source
        bf* Wq = Wt[dir * 3 + 0];
        bf* Wk = Wt[dir * 3 + 1];
        bf* Wv = Wt[dir * 3 + 2];
        const float* bq = bias[dir * 3 + 0];
        const float* bk = bias[dir * 3 + 1];
        const float* bv = bias[dir * 3 + 2];
        bf* O = dir == 0 ? O1 : O2;
        float* csd = cs + (size_t)dir * B * S;

        gemm_nt<bf, false><<<gProj, blkG, 0, stream>>>(Xq, Xq, NOSPLIT, D, Wq, D, bq, Q,  D, D, 0, 0, 0);
        gemm_nt<bf, false><<<gProj, blkG, 0, stream>>>(Xk, Xk, NOSPLIT, D, Wk, D, bk, Kb, D, D, 0, 0, 0);
        gemm_nt<bf, true ><<<gProj, blkG, 0, stream>>>(Xk, Xk, NOSPLIT, D, Wv, D, bv, Vt, M, D, 0, 0, 0);

        for (int c0 = 0; c0 < B; c0 += cb) {
            int cbc = (B - c0 < cb) ? (B - c0) : cb;
            scores_exp<<<dim3(S / BM, S / BN, cbc), blkG, 0, stream>>>(
                Q + c0 * SD, Kb + c0 * SD, E, csd + (size_t)c0 * S, D, rscale);
            scale_vt<<<dim3(cbc * S / 1024, D), blk, 0, stream>>>(
                Vt + (size_t)c0 * S, csd + (size_t)c0 * S, M);
            gemm_nt<bf, false><<<dim3(S / BM, D / BN, cbc), blkG, 0, stream>>>(
                E, E, NOSPLIT, S, Vt + (size_t)c0 * S, M, nullptr,
                O + c0 * SD, D, S, SS, S, (long long)SD);
        }
    }

    // ---- gate (fp32 originals) + final split-A GEMM -> fp32 out ----
    gate_fuse<<<dim3(M * D / 1024), blk, 0, stream>>>(O1, O2, SX, CX, F1, F2, M * D);
    gemm_nt<float, false><<<gProj, blkG, 0, stream>>>(F1, F2, D, D, Wt[6], 2 * D,
                                                     bias[6], out, D, 2 * D, 0, 0, 0);
}

// Round 5
// 692.692 us; speedup vs baseline: 1.2167x; 1.0691x over previous
//
#include <hip/hip_runtime.h>
#include <hip/hip_bf16.h>

#define BM 256   // 256x128 tile, 8 waves (512 thr)
#define BN 128
#define BK 64    // 64 bf16 = 128B per LDS row; single LDS buffer, reg-dbuf pipeline

typedef short short8 __attribute__((ext_vector_type(8)));
typedef float f32x4 __attribute__((ext_vector_type(4)));

using bf = __hip_bfloat16;

static const int NOSPLIT = 1 << 30;

// ---------------------------------------------------------------------------
// async 16B global -> LDS (direct DMA, no VGPR round-trip).
// HW semantics: per-lane dest = wave-uniform lds base + lane*16B.
// ---------------------------------------------------------------------------
__device__ __forceinline__ void gld16(const void* g, void* l)
{
    __builtin_amdgcn_global_load_lds(
        (__attribute__((address_space(1))) void*)g,
        (__attribute__((address_space(3))) void*)l, 16, 0, 0);
}

// LDS offset (ushorts) of k-group kg8 (8 bf16 = 16B slot, 8 slots/row) of row
// `row` under the XOR swizzle: slot = kg8 ^ (row&7). Staging base rows are
// multiples of 8 so writer/reader permutations match. Measured
// SQ_LDS_BANK_CONFLICT = 0 with this layout.
__device__ __forceinline__ int lofs(int row, int kg8)
{
    return row * 64 + ((kg8 ^ (row & 7)) << 3);
}

// ---------------------------------------------------------------------------
// fp32 -> bf16 cast, 4 elems/thread
// ---------------------------------------------------------------------------
__global__ __launch_bounds__(256)
void cast_bf16(const float* __restrict__ src, bf* __restrict__ dst, int n)
{
    int i = (blockIdx.x * 256 + threadIdx.x) * 4;
    if (i >= n) return;
    float4 v = *(const float4*)(src + i);
    bf o[4] = { __float2bfloat16(v.x), __float2bfloat16(v.y),
                __float2bfloat16(v.z), __float2bfloat16(v.w) };
    *(uint2*)(dst + i) = *(const uint2*)o;
}

// ---------------------------------------------------------------------------
// W [Kd][Nd] fp32 -> Wt [Nd][Kd] bf16 via 32x32 LDS tile (+1 pad)
// ---------------------------------------------------------------------------
__global__ __launch_bounds__(256)
void transpose_cast_w(const float* __restrict__ W, bf* __restrict__ Wt,
                      int Kd, int Nd)
{
    __shared__ float tile[32][33];
    int k0 = blockIdx.y * 32, n0 = blockIdx.x * 32;
    int t = threadIdx.x;
    int r = t >> 3, c = (t & 7) * 4;
    float4 v = *(const float4*)(W + (size_t)(k0 + r) * Nd + n0 + c);
    tile[r][c] = v.x; tile[r][c+1] = v.y; tile[r][c+2] = v.z; tile[r][c+3] = v.w;
    __syncthreads();
    bf o[4] = { __float2bfloat16(tile[c][r]),   __float2bfloat16(tile[c+1][r]),
                __float2bfloat16(tile[c+2][r]), __float2bfloat16(tile[c+3][r]) };
    *(uint2*)(Wt + (size_t)(n0 + r) * Kd + k0 + c) = *(const uint2*)o;
}

// ---------------------------------------------------------------------------
// C = A[M,K] @ Bt[N,K]^T + bias; bf16 in, fp32 acc. 256x128 tile, 8 waves
// (4 wm x 2 wn, each wave owns 64x64). Single 48 KB LDS buffer; per K-step:
//   barrier (tile t resident: drains DMA)
//   ds_read h0 frags -> MFMA h0 -> ds_read h1 frags
//   barrier (all LDS reads of tile t done -> buffer free)
//   issue stage(t+1) async DMA into the SAME buffer
//   MFMA h1 (register-only, overlaps DMA flight)
// The vmcnt(0) drain at the next step's first barrier now happens ~600cy
// after DMA issue instead of immediately (r4's stall). Registers are the
// double buffer; LDS stays single -> occupancy preserved (2 blocks/CU,
// enforced via __launch_bounds__(512,4) = VGPR cap 128).
// TC: write C transposed (Ct[n][m], 8B packed). Split-A at k=splitA.
// ---------------------------------------------------------------------------
template <typename CT, bool TC>
__global__ __launch_bounds__(512, 4)
void gemm_nt(const bf* __restrict__ A, const bf* __restrict__ A2, int splitA, int lda,
             const bf* __restrict__ Bt, int ldb,
             const float* __restrict__ bias, CT* __restrict__ C, int ldc,
             int K, long long strA, long long strB, long long strC)
{
    __shared__ __align__(16) ushort sA[BM * 64];   // 32 KB
    __shared__ __align__(16) ushort sB[BN * 64];   // 16 KB

    const int z = blockIdx.z;
    A  += (long long)z * strA;
    A2 += (long long)z * strA;
    Bt += (long long)z * strB;
    C  += (long long)z * strC;

    const int t = threadIdx.x;
    const int m0 = blockIdx.x * BM;
    const int n0 = blockIdx.y * BN;
    const int wave = t >> 6, lane = t & 63;        // 8 waves
    const int wm = wave >> 1, wn = wave & 1;       // 4 x 2
    const int lcol = lane & 15, quad = lane >> 4;
    const int rl = lane >> 3, cslot = lane & 7;    // staging: 8 rows x 8 16B-slots

    auto stage = [&](int kt) {
        const bf* Asrc = (kt < splitA) ? A : A2;
        const int ktt = (kt < splitA) ? kt : kt - splitA;
        const int kg = cslot ^ rl;                  // source-side swizzle
        #pragma unroll
        for (int it = 0; it < 4; ++it) {            // A: 256 rows = 8 waves x 8 x 4
            int br = it * 64 + wave * 8;            // wave-uniform base row
            gld16(Asrc + (size_t)(m0 + br + rl) * lda + ktt + kg * 8, &sA[br * 64]);
        }
        #pragma unroll
        for (int it = 0; it < 2; ++it) {            // B: 128 rows = 8 waves x 8 x 2
            int br = it * 64 + wave * 8;
            gld16(Bt + (size_t)(n0 + br + rl) * ldb + kt + kg * 8, &sB[br * 64]);
        }
    };

    f32x4 acc[4][4] = {};

    stage(0);
    for (int kt = 0; kt < K; kt += BK) {
        __syncthreads();                 // tile kt resident (drains async DMA)

        short8 af[4], bfr[4];
        #pragma unroll
        for (int i = 0; i < 4; ++i)
            af[i] = *(const short8*)&sA[lofs(wm * 64 + i * 16 + lcol, quad)];
        #pragma unroll
        for (int j = 0; j < 4; ++j)
            bfr[j] = *(const short8*)&sB[lofs(wn * 64 + j * 16 + lcol, quad)];
        #pragma unroll
        for (int i = 0; i < 4; ++i)
            #pragma unroll
            for (int j = 0; j < 4; ++j)
                acc[i][j] = __builtin_amdgcn_mfma_f32_16x16x32_bf16(af[i], bfr[j], acc[i][j], 0, 0, 0);

        short8 ag[4], bg[4];             // h1 fragments (read before buffer reuse)
        #pragma unroll
        for (int i = 0; i < 4; ++i)
            ag[i] = *(const short8*)&sA[lofs(wm * 64 + i * 16 + lcol, 4 + quad)];
        #pragma unroll
        for (int j = 0; j < 4; ++j)
            bg[j] = *(const short8*)&sB[lofs(wn * 64 + j * 16 + lcol, 4 + quad)];

        __syncthreads();                 // all reads of tile kt done -> buffer free
        if (kt + BK < K) stage(kt + BK); // async DMA overlaps MFMA h1 below

        #pragma unroll
        for (int i = 0; i < 4; ++i)
            #pragma unroll
            for (int j = 0; j < 4; ++j)
                acc[i][j] = __builtin_amdgcn_mfma_f32_16x16x32_bf16(ag[i], bg[j], acc[i][j], 0, 0, 0);
    }

    #pragma unroll
    for (int j = 0; j < 4; ++j) {
        int col = n0 + wn * 64 + j * 16 + lcol;
        float bv = bias ? bias[col] : 0.0f;
        #pragma unroll
        for (int i = 0; i < 4; ++i) {
            int row = m0 + wm * 64 + i * 16 + quad * 4;
            if (!TC) {
                #pragma unroll
                for (int r4 = 0; r4 < 4; ++r4)
                    C[(size_t)(row + r4) * ldc + col] = (CT)(acc[i][j][r4] + bv);
            } else {
                bf o[4];
                #pragma unroll
                for (int r4 = 0; r4 < 4; ++r4)
                    o[r4] = __float2bfloat16(acc[i][j][r4] + bv);
                *(uint2*)((bf*)C + (size_t)col * ldc + row) = *(const uint2*)o;
            }
        }
    }
}

// ---------------------------------------------------------------------------
// E[q,k] = exp((Q[q,:].K[k,:]) * rscale) + colsum over q (softmax over QUERY
// axis). z-batched. Grid (S/BM, S/BN, cb). S = 2048 fixed.
// 256(q) x 128(k) tile, 8 waves. MFMA operands SWAPPED (K-frag first) so the
// C/D register group holds 4 consecutive k: E row-stores are packed 8B.
// Same reg-dbuf pipeline as gemm_nt.
// ---------------------------------------------------------------------------
__global__ __launch_bounds__(512, 4)
void scores_exp(const bf* __restrict__ Q, const bf* __restrict__ Km,
                bf* __restrict__ E, float* __restrict__ colsum,
                int Dd, float rscale)
{
    const int S = 2048;
    __shared__ __align__(16) ushort sA[BM * 64];
    __shared__ __align__(16) ushort sB[BN * 64];

    const int z = blockIdx.z;
    Q  += (size_t)z * S * Dd;
    Km += (size_t)z * S * Dd;
    E  += (size_t)z * S * S;
    colsum += (size_t)z * S;

    const int t = threadIdx.x;
    const int m0 = blockIdx.x * BM;     // Q rows
    const int n0 = blockIdx.y * BN;     // K rows
    const int wave = t >> 6, lane = t & 63;
    const int wm = wave >> 1, wn = wave & 1;
    const int lcol = lane & 15, quad = lane >> 4;
    const int rl = lane >> 3, cslot = lane & 7;

    auto stage = [&](int kt) {
        const int kg = cslot ^ rl;
        #pragma unroll
        for (int it = 0; it < 4; ++it) {
            int br = it * 64 + wave * 8;
            gld16(Q + (size_t)(m0 + br + rl) * Dd + kt + kg * 8, &sA[br * 64]);
        }
        #pragma unroll
        for (int it = 0; it < 2; ++it) {
            int br = it * 64 + wave * 8;
            gld16(Km + (size_t)(n0 + br + rl) * Dd + kt + kg * 8, &sB[br * 64]);
        }
    };

    f32x4 acc[4][4] = {};       // acc[a][b]: rows = K-range a, cols = Q-range b

    stage(0);
    for (int kt = 0; kt < Dd; kt += BK) {
        __syncthreads();

        short8 af[4], bfr[4];
        #pragma unroll
        for (int i = 0; i < 4; ++i)
            af[i] = *(const short8*)&sA[lofs(wm * 64 + i * 16 + lcol, quad)];
        #pragma unroll
        for (int j = 0; j < 4; ++j)
            bfr[j] = *(const short8*)&sB[lofs(wn * 64 + j * 16 + lcol, quad)];
        #pragma unroll
        for (int a = 0; a < 4; ++a)
            #pragma unroll
            for (int b = 0; b < 4; ++b)
                acc[a][b] = __builtin_amdgcn_mfma_f32_16x16x32_bf16(bfr[a], af[b], acc[a][b], 0, 0, 0);

        short8 ag[4], bg[4];
        #pragma unroll
        for (int i = 0; i < 4; ++i)
            ag[i] = *(const short8*)&sA[lofs(wm * 64 + i * 16 + lcol, 4 + quad)];
        #pragma unroll
        for (int j = 0; j < 4; ++j)
            bg[j] = *(const short8*)&sB[lofs(wn * 64 + j * 16 + lcol, 4 + quad)];

        __syncthreads();
        if (kt + BK < Dd) stage(kt + BK);

        #pragma unroll
        for (int a = 0; a < 4; ++a)
            #pragma unroll
            for (int b = 0; b < 4; ++b)
                acc[a][b] = __builtin_amdgcn_mfma_f32_16x16x32_bf16(bg[a], ag[b], acc[a][b], 0, 0, 0);
    }

    // epilogue: rows of the C tile are k (first operand = K fragments),
    // cols are q. Register r4 walks 4 consecutive k -> packed 8B stores.
    #pragma unroll
    for (int a = 0; a < 4; ++a) {
        const int kk = n0 + wn * 64 + a * 16 + quad * 4;
        f32x4 csum = {0.f, 0.f, 0.f, 0.f};
        #pragma unroll
        for (int b = 0; b < 4; ++b) {
            const int q = m0 + wm * 64 + b * 16 + lcol;
            bf o[4];
            #pragma unroll
            for (int r = 0; r < 4; ++r) {
                float e = __expf(acc[a][b][r] * rscale);
                o[r] = __float2bfloat16(e);
                csum[r] += e;
            }
            *(uint2*)(E + (size_t)q * S + kk) = *(const uint2*)o;
        }
        // reduce over q within the wave: 16-lane lcol group (quad preserved)
        #pragma unroll
        for (int msk = 1; msk < 16; msk <<= 1) {
            csum[0] += __shfl_xor(csum[0], msk);
            csum[1] += __shfl_xor(csum[1], msk);
            csum[2] += __shfl_xor(csum[2], msk);
            csum[3] += __shfl_xor(csum[3], msk);
        }
        if (lcol == 0) {
            atomicAdd(&colsum[kk + 0], csum[0]);
            atomicAdd(&colsum[kk + 1], csum[1]);
            atomicAdd(&colsum[kk + 2], csum[2]);
            atomicAdd(&colsum[kk + 3], csum[3]);
        }
    }
}

// Vt[d][col] /= cs[col], over a column window. Grid (ncols/1024, 768).
__global__ __launch_bounds__(256)
void scale_vt(bf* __restrict__ Vt, const float* __restrict__ cs, int ldv)
{
    int col = (blockIdx.x * 256 + threadIdx.x) * 4;
    bf* p = Vt + (size_t)blockIdx.y * ldv + col;
    bf v[4]; *(uint2*)v = *(const uint2*)p;
    float4 c4 = *(const float4*)(cs + col);
    v[0] = __float2bfloat16(__bfloat162float(v[0]) / c4.x);
    v[1] = __float2bfloat16(__bfloat162float(v[1]) / c4.y);
    v[2] = __float2bfloat16(__bfloat162float(v[2]) / c4.z);
    v[3] = __float2bfloat16(__bfloat162float(v[3]) / c4.w);
    *(uint2*)p = *(const uint2*)v;
}

// gating from fp32 originals: F1 = a2*sx+(1-a2)*cx ; F2 = a1*cx+(1-a1)*sx
__global__ __launch_bounds__(256)
void gate_fuse(const bf* __restrict__ O1, const bf* __restrict__ O2,
               const float* __restrict__ SX, const float* __restrict__ CX,
               bf* __restrict__ F1, bf* __restrict__ F2, int n)
{
    int i = (blockIdx.x * 256 + threadIdx.x) * 4;
    if (i >= n) return;
    bf o1[4], o2[4], f1[4], f2[4];
    *(uint2*)o1 = *(const uint2*)(O1 + i);
    *(uint2*)o2 = *(const uint2*)(O2 + i);
    float4 sx = *(const float4*)(SX + i);
    float4 cx = *(const float4*)(CX + i);
    #pragma unroll
    for (int e = 0; e < 4; ++e) {
        float s = (&sx.x)[e], c = (&cx.x)[e];
        float a1 = 1.0f / (1.0f + __expf(-tanhf(__bfloat162float(o1[e]))));
        float a2 = 1.0f / (1.0f + __expf(-tanhf(__bfloat162float(o2[e]))));
        f1[e] = __float2bfloat16(a2 * s + (1.0f - a2) * c);
        f2[e] = __float2bfloat16(a1 * c + (1.0f - a1) * s);
    }
    *(uint2*)(F1 + i) = *(const uint2*)f1;
    *(uint2*)(F2 + i) = *(const uint2*)f2;
}

extern "C" void kernel_launch(void* const* d_in, const int* in_sizes, int n_in,
                              void* d_out, int out_size, void* d_ws, size_t ws_size,
                              hipStream_t stream)
{
    const int B = 8, S = 2048, D = 768;
    const int M = B * S;                        // 16384

    const float* SX = (const float*)d_in[0];
    const float* CX = (const float*)d_in[1];
    const float* Wsrc[7] = { (const float*)d_in[2],  (const float*)d_in[4],
                             (const float*)d_in[6],  (const float*)d_in[8],
                             (const float*)d_in[10], (const float*)d_in[12],
                             (const float*)d_in[14] };
    const float* bias[7] = { (const float*)d_in[3],  (const float*)d_in[5],
                             (const float*)d_in[7],  (const float*)d_in[9],
                             (const float*)d_in[11], (const float*)d_in[13],
                             (const float*)d_in[15] };
    float* out = (float*)d_out;

    // ---- workspace layout: fixed 160.6 MB + adaptive E chunk ----
    char* w = (char*)d_ws;
    const size_t MD  = (size_t)M * D * sizeof(bf);       // 25.17 MB
    const size_t WSZ = (size_t)D * D * sizeof(bf);       // 1.18 MB
    const size_t SSB = (size_t)S * S * sizeof(bf);       // 8.39 MB per E batch
    bf* Xs = (bf*)(w);
    bf* Xc = (bf*)(w + MD);
    bf* Wt[7];
    for (int i = 0; i < 7; ++i) Wt[i] = (bf*)(w + 2 * MD + i * WSZ);  // Wtf = slots 6,7
    char* base2 = w + 2 * MD + 8 * WSZ;
    bf* Q  = (bf*)(base2);
    bf* Kb = (bf*)(base2 + MD);
    bf* Vt = (bf*)(base2 + 2 * MD);
    bf* O1 = (bf*)(base2 + 3 * MD);
    float* cs = (float*)(base2 + 4 * MD);                // 2*B*S fp32 = 128 KB
    char* Eb0 = base2 + 4 * MD + (size_t)2 * B * S * sizeof(float);
    bf* E = (bf*)Eb0;
    int cb;
    {
        size_t fixed = (size_t)(Eb0 - w);
        size_t avail = ws_size > fixed ? ws_size - fixed : SSB;
        long long c = (long long)(avail / SSB);
        cb = c < 1 ? 1 : (c > 8 ? 8 : (int)c);
    }
    // aliases (stream-order verified in r6, which passed):
    bf* O2 = Xs;
    bf* F1 = Kb;
    bf* F2 = Vt;

    (void)hipMemsetAsync(cs, 0, (size_t)2 * B * S * sizeof(float), stream);

    dim3 blk(256);
    dim3 blkG(512);
    {
        int n = M * D;
        cast_bf16<<<dim3(n / 1024), blk, 0, stream>>>(SX, Xs, n);
        cast_bf16<<<dim3(n / 1024), blk, 0, stream>>>(CX, Xc, n);
        for (int i = 0; i < 6; ++i)
            transpose_cast_w<<<dim3(D / 32, D / 32), blk, 0, stream>>>(Wsrc[i], Wt[i], D, D);
        transpose_cast_w<<<dim3(D / 32, 2 * D / 32), blk, 0, stream>>>(Wsrc[6], Wt[6], 2 * D, D);
    }

    dim3 gProj(M / BM, D / BN);      // 64 x 6
    const float rscale = 1.0f / sqrtf((float)D);
    const size_t SD = (size_t)S * D;
    const long long SS = (long long)S * S;

    for (int dir = 0; dir < 2; ++dir) {
        const bf* Xq = dir == 0 ? Xs : Xc;   // queries source
        const bf* Xk = dir == 0 ? Xc : Xs;   // keys/values source
        bf* Wq = Wt[dir * 3 + 0];
        bf* Wk = Wt[dir * 3 + 1];
        bf* Wv = Wt[dir * 3 + 2];
        const float* bq = bias[dir * 3 + 0];
        const float* bk = bias[dir * 3 + 1];
        const float* bv = bias[dir * 3 + 2];
        bf* O = dir == 0 ? O1 : O2;
        float* csd = cs + (size_t)dir * B * S;

        gemm_nt<bf, false><<<gProj, blkG, 0, stream>>>(Xq, Xq, NOSPLIT, D, Wq, D, bq, Q,  D, D, 0, 0, 0);
        gemm_nt<bf, false><<<gProj, blkG, 0, stream>>>(Xk, Xk, NOSPLIT, D, Wk, D, bk, Kb, D, D, 0, 0, 0);
        gemm_nt<bf, true ><<<gProj, blkG, 0, stream>>>(Xk, Xk, NOSPLIT, D, Wv, D, bv, Vt, M, D, 0, 0, 0);

        for (int c0 = 0; c0 < B; c0 += cb) {
            int cbc = (B - c0 < cb) ? (B - c0) : cb;
            scores_exp<<<dim3(S / BM, S / BN, cbc), blkG, 0, stream>>>(
                Q + c0 * SD, Kb + c0 * SD, E, csd + (size_t)c0 * S, D, rscale);
            scale_vt<<<dim3(cbc * S / 1024, D), blk, 0, stream>>>(
                Vt + (size_t)c0 * S, csd + (size_t)c0 * S, M);
            gemm_nt<bf, false><<<dim3(S / BM, D / BN, cbc), blkG, 0, stream>>>(
                E, E, NOSPLIT, S, Vt + (size_t)c0 * S, M, nullptr,
                O + c0 * SD, D, S, SS, S, (long long)SD);
        }
    }

    // ---- gate (fp32 originals) + final split-A GEMM -> fp32 out ----
    gate_fuse<<<dim3(M * D / 1024), blk, 0, stream>>>(O1, O2, SX, CX, F1, F2, M * D);
    gemm_nt<float, false><<<gProj, blkG, 0, stream>>>(F1, F2, D, D, Wt[6], 2 * D,
                                                     bias[6], out, D, 2 * D, 0, 0, 0);
}